// Round 5
// baseline (304.076 us; speedup 1.0000x reference)
//
#include <hip/hip_runtime.h>
#include <hip/hip_bf16.h>

#define B_  32
#define N_  2048
#define M_  2048
#define D_  128

typedef __attribute__((ext_vector_type(4)))  float f32x4;
typedef __attribute__((ext_vector_type(16))) float f32x16;
typedef __attribute__((ext_vector_type(8)))  short bf16x8;

// log2(e) / sqrt(128): softmax in exp2 domain; folded into Q's bf16 cast.
static constexpr float SCALE2 = 1.4426950408889634f / 11.313708498984761f;

__device__ __forceinline__ unsigned short f2bf(float x) {
  union { float f; unsigned u; } c; c.f = x;
  unsigned u = c.u;
  return (unsigned short)((u + 0x7FFFu + ((u >> 16) & 1u)) >> 16);  // RNE
}

__device__ __forceinline__ unsigned pk2bf(float a, float b) {
  float2 f2; f2.x = a; f2.y = b;
  __hip_bfloat162 h = __float22bfloat162_rn(f2);   // v_cvt_pk_bf16_f32
  union { __hip_bfloat162 h; unsigned u; } c; c.h = h;
  return c.u;
}

// async global->LDS, 16B per lane; LDS dest = wave-uniform base + lane*16
__device__ __forceinline__ void gl2lds16(const void* gp, void* lp) {
  __builtin_amdgcn_global_load_lds(
      (const __attribute__((address_space(1))) unsigned int*)gp,
      (__attribute__((address_space(3))) unsigned int*)lp, 16, 0, 0);
}

// ---------- prep: fp32 -> bf16 for Q (scale=SCALE2) and K (scale=1) ----------
__global__ __launch_bounds__(256) void cvt_qk_kernel(
    const float* __restrict__ Q, const float* __restrict__ K,
    unsigned short* __restrict__ Qb, unsigned short* __restrict__ Kb, int n4) {
  int i = blockIdx.x * 256 + threadIdx.x;
  if (i >= n4) return;
  const float* src = blockIdx.y ? K : Q;
  unsigned short* dst = blockIdx.y ? Kb : Qb;
  const float sc = blockIdx.y ? 1.0f : SCALE2;
  const float4 v = reinterpret_cast<const float4*>(src)[i];
  ushort4 o;
  o.x = f2bf(v.x * sc); o.y = f2bf(v.y * sc);
  o.z = f2bf(v.z * sc); o.w = f2bf(v.w * sc);
  reinterpret_cast<ushort4*>(dst)[i] = o;
}

// ---------- pass 1: vscale[m] = 2^-16 / sum_n 2^(s2[n,m]-16) ----------
// grid (M/128, B); 4 waves x 32m (K frags in regs, 32x32x16 A-operand);
// Q staged in LDS 32n at a time, single-buffer two-barrier.
__global__ __launch_bounds__(256, 2) void colstats_kernel(
    const unsigned short* __restrict__ Qb, const unsigned short* __restrict__ Kb,
    float* __restrict__ vscale) {
  const int b    = blockIdx.y;
  const int wv   = threadIdx.x >> 6;
  const int lane = threadIdx.x & 63;
  const int l31  = lane & 31;
  const int h    = lane >> 5;
  const int mw   = blockIdx.x * 128 + wv * 32;

  // qbuf rows n-local (256B = 16 chunks), chunk c stored at pos c ^ (n&15)
  __shared__ unsigned short qbuf[32 * 128];   // 8 KB

  // K as A-operand: A[row=m=l31][k = kc*16 + h*8 + j] — in registers
  bf16x8 kf[8];
  {
    const unsigned short* Kr = Kb + ((size_t)b * M_ + mw + l31) * D_ + h * 8;
    #pragma unroll
    for (int kc = 0; kc < 8; ++kc)
      kf[kc] = *reinterpret_cast<const bf16x8*>(Kr + kc * 16);
  }

  const unsigned short* Qbb = Qb + (size_t)b * N_ * D_;
  float ps[16];
  #pragma unroll
  for (int r = 0; r < 16; ++r) ps[r] = 0.f;

  for (int nt = 0; nt < N_; nt += 32) {
    __syncthreads();                          // previous-tile reads done
    #pragma unroll
    for (int i = 0; i < 2; ++i) {
      int s = (wv * 2 + i) * 64 + lane;       // 16B slot 0..511
      int nloc = s >> 4, c = (s & 15) ^ (nloc & 15);
      gl2lds16(Qbb + (size_t)(nt + nloc) * D_ + c * 8,
               (char*)qbuf + (size_t)s * 16);
    }
    __syncthreads();                          // staging visible

    // S^T tile 32m x 32n: A=K(regs), B=Q(LDS): B[col=n=l31][k=kc*16+h*8+j]
    f32x16 acc = {};
    #pragma unroll
    for (int kc = 0; kc < 8; ++kc) {
      int cq = (kc * 2 + h) ^ (l31 & 15);
      bf16x8 qfr = *reinterpret_cast<const bf16x8*>(qbuf + l31 * 128 + cq * 8);
      acc = __builtin_amdgcn_mfma_f32_32x32x16_bf16(kf[kc], qfr, acc, 0, 0, 0);
    }
    // acc[r] = s2[m = (r&3)+8*(r>>2)+4h][n = nt + l31]
    #pragma unroll
    for (int r = 0; r < 16; ++r) ps[r] += exp2f(acc[r] - 16.f);
  }
  // reduce over the 32 columns held by lanes sharing h
  #pragma unroll
  for (int r = 0; r < 16; ++r) {
    ps[r] += __shfl_xor(ps[r], 1);
    ps[r] += __shfl_xor(ps[r], 2);
    ps[r] += __shfl_xor(ps[r], 4);
    ps[r] += __shfl_xor(ps[r], 8);
    ps[r] += __shfl_xor(ps[r], 16);
  }
  if (l31 == 0) {
    #pragma unroll
    for (int r = 0; r < 16; ++r)
      vscale[(size_t)b * M_ + mw + (r & 3) + 8 * (r >> 2) + 4 * h] =
          0x1p-16f / ps[r];
  }
}

// ---------- prep: V (b,m,d) fp32 -> Vt (b,d,m) bf16, folding vscale[m] ----------
__global__ __launch_bounds__(256) void transpose_v_kernel(
    const float* __restrict__ V, const float* __restrict__ vscale,
    unsigned short* __restrict__ Vt) {
  const int b = blockIdx.z;
  const int m0 = blockIdx.x * 64;
  const int d0 = blockIdx.y * 64;
  __shared__ float t[64][65];
  const int tid = threadIdx.x;
  const int r = tid >> 2;   // 0..63
  const int c = tid & 3;    // 0..3
  const float* src = V + ((size_t)b * M_ + (m0 + r)) * D_ + d0 + c * 16;
  #pragma unroll
  for (int i = 0; i < 4; ++i) {
    float4 v = reinterpret_cast<const float4*>(src)[i];
    t[r][c * 16 + i * 4 + 0] = v.x;
    t[r][c * 16 + i * 4 + 1] = v.y;
    t[r][c * 16 + i * 4 + 2] = v.z;
    t[r][c * 16 + i * 4 + 3] = v.w;
  }
  __syncthreads();
  const float* vs = vscale + (size_t)b * M_ + m0 + c * 16;
  ushort4 ob[4];
  #pragma unroll
  for (int i = 0; i < 4; ++i) {
    float4 s4 = reinterpret_cast<const float4*>(vs)[i];
    ob[i].x = f2bf(t[c * 16 + i * 4 + 0][r] * s4.x);
    ob[i].y = f2bf(t[c * 16 + i * 4 + 1][r] * s4.y);
    ob[i].z = f2bf(t[c * 16 + i * 4 + 2][r] * s4.z);
    ob[i].w = f2bf(t[c * 16 + i * 4 + 3][r] * s4.w);
  }
  ushort4* dst = reinterpret_cast<ushort4*>(
      Vt + ((size_t)b * D_ + d0 + r) * M_ + m0 + c * 16);
  #pragma unroll
  for (int i = 0; i < 4; ++i) dst[i] = ob[i];
}

// ---------- pass 2: O[n,d] = sum_m 2^(s2[n,m]) * V'[m,d] ----------
// grid (N/128, B); 4 waves x 32n over full 128d; m-chunks of 32; 32x32x16 MFMA
// throughout (2x FLOP per LDS byte vs 16x16x32). Single-buffer two-barrier.
__global__ __launch_bounds__(256, 2) void attn_out_kernel(
    const unsigned short* __restrict__ Qb, const unsigned short* __restrict__ Kb,
    const unsigned short* __restrict__ Vt, float* __restrict__ out) {
  const int b    = blockIdx.y;
  const int wv   = threadIdx.x >> 6;
  const int lane = threadIdx.x & 63;
  const int l31  = lane & 31;
  const int h    = lane >> 5;
  const int nq   = blockIdx.x * 128 + wv * 32;

  __shared__ unsigned short kbuf[32 * 128];    // 8 KB: rows m (256B, 16 chunks)
  __shared__ unsigned short vbuf[128 * 32];    // 8 KB: rows d (64B, 4 chunks)
  __shared__ unsigned short pbuf[4][32 * 36];  // per-wave P^T [n][m], stride 72B

  // Q as B-operand: B[col=n=l31][k = kc*16 + h*8 + j] — loop invariant regs
  bf16x8 qf[8];
  {
    const unsigned short* Qr = Qb + ((size_t)b * N_ + nq + l31) * D_ + h * 8;
    #pragma unroll
    for (int kc = 0; kc < 8; ++kc)
      qf[kc] = *reinterpret_cast<const bf16x8*>(Qr + kc * 16);
  }

  f32x16 o[4];
  #pragma unroll
  for (int dt = 0; dt < 4; ++dt) o[dt] = (f32x16){};

  const unsigned short* Kbb = Kb + (size_t)b * M_ * D_;
  const unsigned short* Vbb = Vt + (size_t)b * D_ * M_;
  unsigned short* pw = pbuf[wv];

  for (int m0 = 0; m0 < M_; m0 += 32) {
    __syncthreads();                           // previous-chunk reads done
    #pragma unroll
    for (int i = 0; i < 2; ++i) {
      int s = (wv * 2 + i) * 64 + lane;        // 16B slot 0..511
      // K tile: slot s = row m (s>>4), pos (s&15) holds chunk ((s&15)^(m&15))
      int mloc = s >> 4, ck = (s & 15) ^ (mloc & 15);
      gl2lds16(Kbb + (size_t)(m0 + mloc) * D_ + ck * 8,
               (char*)kbuf + (size_t)s * 16);
      // V tile: slot s = row d (s>>2), pos (s&3) holds chunk ((s&3)^((d>>1)&3))
      int dloc = s >> 2, cv = (s & 3) ^ ((dloc >> 1) & 3);
      gl2lds16(Vbb + (size_t)dloc * M_ + m0 + cv * 8,
               (char*)vbuf + (size_t)s * 16);
    }
    __syncthreads();                           // staging visible

    // S^T tile 32m x 32n: A = K (LDS), B = Q (regs)
    f32x16 s_acc = {};
    #pragma unroll
    for (int kc = 0; kc < 8; ++kc) {
      int ck = (kc * 2 + h) ^ (l31 & 15);
      bf16x8 kfr = *reinterpret_cast<const bf16x8*>(kbuf + l31 * 128 + ck * 8);
      s_acc = __builtin_amdgcn_mfma_f32_32x32x16_bf16(kfr, qf[kc], s_acc, 0, 0, 0);
    }
    // s_acc[r]: m = (r&3)+8*(r>>2)+4h (4 consecutive m per reg-group), n = l31.
    // P store: one ds_write_b64 (4 packed bf16) per reg-group.
    #pragma unroll
    for (int g = 0; g < 4; ++g) {
      uint2 w;
      w.x = pk2bf(exp2f(s_acc[4 * g + 0]), exp2f(s_acc[4 * g + 1]));
      w.y = pk2bf(exp2f(s_acc[4 * g + 2]), exp2f(s_acc[4 * g + 3]));
      *reinterpret_cast<uint2*>(pw + l31 * 36 + g * 8 + h * 4) = w;
    }
    // P A-fragments: A[row=n=l31][k=m = km*16 + h*8 + j] (same-wave LDS RAW)
    bf16x8 pa0 = *reinterpret_cast<const bf16x8*>(pw + l31 * 36 + h * 8);
    bf16x8 pa1 = *reinterpret_cast<const bf16x8*>(pw + l31 * 36 + 16 + h * 8);
    // PV: o[n][d] += P * V'; B = V' (LDS): B[col=d][k=m]
    #pragma unroll
    for (int dt = 0; dt < 4; ++dt) {
      const int d = dt * 32 + l31;
      int c0 = h ^ ((d >> 1) & 3);
      int c1 = (2 + h) ^ ((d >> 1) & 3);
      bf16x8 v0 = *reinterpret_cast<const bf16x8*>(vbuf + d * 32 + c0 * 8);
      o[dt] = __builtin_amdgcn_mfma_f32_32x32x16_bf16(pa0, v0, o[dt], 0, 0, 0);
      bf16x8 v1 = *reinterpret_cast<const bf16x8*>(vbuf + d * 32 + c1 * 8);
      o[dt] = __builtin_amdgcn_mfma_f32_32x32x16_bf16(pa1, v1, o[dt], 0, 0, 0);
    }
  }

  // epilogue: o[dt][r] = O[nq + (r&3)+8*(r>>2)+4h][dt*32 + l31]
  #pragma unroll
  for (int dt = 0; dt < 4; ++dt)
    #pragma unroll
    for (int r = 0; r < 16; ++r) {
      int nrow = (r & 3) + 8 * (r >> 2) + 4 * h;
      out[((size_t)b * N_ + nq + nrow) * D_ + dt * 32 + l31] = o[dt][r];
    }
}

extern "C" void kernel_launch(void* const* d_in, const int* in_sizes, int n_in,
                              void* d_out, int out_size, void* d_ws, size_t ws_size,
                              hipStream_t stream) {
  const float* Q = (const float*)d_in[0];
  const float* K = (const float*)d_in[1];
  const float* V = (const float*)d_in[2];
  float* out = (float*)d_out;

  const size_t elems = (size_t)B_ * N_ * D_;  // 8,388,608 per tensor
  unsigned short* Qb = (unsigned short*)d_ws;
  unsigned short* Kb = Qb + elems;
  unsigned short* Vt = Kb + elems;
  float* vscale = (float*)(Vt + elems);       // 32*2048 floats
  // total ws use: 3*16 MB + 256 KB ~= 50.6 MB

  const int n4 = (int)(elems / 4);
  cvt_qk_kernel<<<dim3(n4 / 256, 2), 256, 0, stream>>>(Q, K, Qb, Kb, n4);
  colstats_kernel<<<dim3(M_ / 128, B_), 256, 0, stream>>>(Qb, Kb, vscale);
  transpose_v_kernel<<<dim3(M_ / 64, D_ / 64, B_), 256, 0, stream>>>(V, vscale, Vt);
  attn_out_kernel<<<dim3(N_ / 128, B_), 256, 0, stream>>>(Qb, Kb, Vt, out);
}